// Round 2
// 5728.545 us; speedup vs baseline: 2.3293x; 2.3293x over previous
//
#include <hip/hip_runtime.h>
#include <stdint.h>

typedef unsigned short u16;
typedef unsigned int   u32;
typedef unsigned long long u64;

#define B_  64
#define T_  2048
#define I_  512
#define H_  512
#define G_  2048   // 4*H

typedef __attribute__((ext_vector_type(8))) __bf16 bf16x8;
typedef __attribute__((ext_vector_type(4))) float  f32x4;

// ---- workspace layout (bytes) ----
#define OFF_XB    0ull                         // x as bf16, [B][T][I]        128 MB
#define OFF_GX    134217728ull                 // gates_x bf16 [T][B][G]      512 MB
#define OFF_WXP   (OFF_GX + 536870912ull)      // Wx permuted bf16 [G][I]       2 MB
#define OFF_WHP   (OFF_WXP + 2097152ull)       // Wh permuted bf16 [G][H]       2 MB
#define OFF_BIAS  (OFF_WHP + 2097152ull)       // (bx+bh) permuted f32 [G]      8 KB
#define OFF_HBUF  (OFF_BIAS + 8192ull)         // tagged h, 2 x [64][256] u64 256 KB
#define WS_NEEDED (OFF_HBUF + 262144ull)

__device__ __forceinline__ float bf2f(u16 u) {
  union { float f; u32 u; } c; c.u = ((u32)u) << 16; return c.f;
}
__device__ __forceinline__ u16 f2bf(float f) {
  union { float f; u32 u; } c; c.f = f;
  u32 u = c.u;
  return (u16)((u + 0x7FFFu + ((u >> 16) & 1u)) >> 16);
}
__device__ __forceinline__ float sigmoidf_(float x) {
  return __fdividef(1.f, 1.f + __expf(-x));
}
__device__ __forceinline__ float tanhf_(float x) {
  return 1.f - __fdividef(2.f, 1.f + __expf(2.f * x));
}
__device__ __forceinline__ void async16(const u16* g, u16* l) {
  __builtin_amdgcn_global_load_lds((const __attribute__((address_space(1))) void*)g,
                                   (__attribute__((address_space(3))) void*)l,
                                   16, 0, 0);
}

// ---------------------------------------------------------------------------
// prep: permute+convert weights to bf16 (col order n = k*4 + gate), bias sum,
// zero BOTH tagged-h buffers (tag 0 == h_0 valid; ws re-poisoned every launch)
// ---------------------------------------------------------------------------
__global__ void __launch_bounds__(256)
prep_misc(const float* __restrict__ wx, const float* __restrict__ bx,
          const float* __restrict__ wh, const float* __restrict__ bh,
          u16* __restrict__ wxp, u16* __restrict__ whp,
          float* __restrict__ bias, u32* __restrict__ hbuf0)
{
  int idx = blockIdx.x * 256 + threadIdx.x;      // 0 .. 1048575
  int n = idx >> 9, k = idx & 511;
  long r = (long)(((n & 3) << 9) | (n >> 2)) * 512 + k;  // original row g*512+khid
  wxp[idx] = f2bf(wx[r]);
  whp[idx] = f2bf(wh[r]);
  if (idx < G_) {
    int rb = ((idx & 3) << 9) | (idx >> 2);
    bias[idx] = bx[rb] + bh[rb];
  }
  if (idx < 65536) hbuf0[idx] = 0u;              // zero 2 x 128KB tagged h
}

// ---------------------------------------------------------------------------
// convert x (fp32) -> bf16, same [B][T][I] layout
// ---------------------------------------------------------------------------
__global__ void __launch_bounds__(256)
conv_x(const float* __restrict__ x, u16* __restrict__ xb)
{
  long idx = ((long)blockIdx.x * 256 + threadIdx.x) * 4;
  float4 v = *(const float4*)(x + idx);
  u64 pk = (u64)f2bf(v.x) | ((u64)f2bf(v.y) << 16) |
           ((u64)f2bf(v.z) << 32) | ((u64)f2bf(v.w) << 48);
  *(u64*)(xb + idx) = pk;
}

// ---------------------------------------------------------------------------
// gates_x GEMM: gx[t][b][n] = sum_k x[b][t][k]*WxP[n][k] + biasP[n]
// (unchanged m97-structure 128x128 tile kernel)
// ---------------------------------------------------------------------------
__global__ void __launch_bounds__(256)
gemm_gates(const u16* __restrict__ xb, const u16* __restrict__ wxp,
           const float* __restrict__ bias, u16* __restrict__ gx)
{
  __shared__ __align__(16) u16 smem[16384];
  const int tid  = threadIdx.x;
  const int lane = tid & 63;
  const int w    = tid >> 6;
  const int tn   = blockIdx.x;
  const int tm   = blockIdx.y;
  const int wr   = w >> 1, wc = w & 1;

  const u16* gsrc[8];
  u16* ldst[8];
#pragma unroll
  for (int q = 0; q < 8; ++q) {
    int c   = w * 8 + q;
    int isB = c >= 16;
    int cc  = c & 15;
    int rloc = (cc >> 1) * 16 + (lane & 15);
    int koff = (cc & 1) * 32 + ((lane >> 4) << 3);
    if (!isB) {
      int m = tm * 128 + rloc;
      int bb = m & 63, tt = m >> 6;
      gsrc[q] = xb + (long)bb * (T_ * I_) + (long)tt * I_ + koff;
    } else {
      int n = tn * 128 + rloc;
      gsrc[q] = wxp + (long)n * I_ + koff;
    }
    ldst[q] = smem + isB * 8192 + cc * 512;
  }

  f32x4 acc[4][4] = {};
  for (int k0 = 0; k0 < I_; k0 += 64) {
#pragma unroll
    for (int q = 0; q < 8; ++q) async16(gsrc[q] + k0, ldst[q]);
    __syncthreads();
#pragma unroll
    for (int kb = 0; kb < 2; ++kb) {
      bf16x8 a[4], b[4];
#pragma unroll
      for (int i = 0; i < 4; ++i)
        a[i] = *(const bf16x8*)(smem + ((wr * 4 + i) * 2 + kb) * 512 + lane * 8);
#pragma unroll
      for (int j = 0; j < 4; ++j)
        b[j] = *(const bf16x8*)(smem + 8192 + ((wc * 4 + j) * 2 + kb) * 512 + lane * 8);
#pragma unroll
      for (int i = 0; i < 4; ++i)
#pragma unroll
        for (int j = 0; j < 4; ++j)
          acc[i][j] = __builtin_amdgcn_mfma_f32_16x16x32_bf16(a[i], b[j], acc[i][j], 0, 0, 0);
    }
    __syncthreads();
  }

#pragma unroll
  for (int j = 0; j < 4; ++j) {
    int n = tn * 128 + (wc * 4 + j) * 16 + (lane & 15);
    float bv = bias[n];
#pragma unroll
    for (int i = 0; i < 4; ++i) {
      int mbase = tm * 128 + (wr * 4 + i) * 16 + ((lane >> 4) << 2);
#pragma unroll
      for (int r = 0; r < 4; ++r) {
        int m = mbase + r;
        int tt = m >> 6, bb = m & 63;
        gx[(long)tt * (B_ * G_) + (long)bb * G_ + n] = f2bf(acc[i][j][r] + bv);
      }
    }
  }
}

// ---------------------------------------------------------------------------
// Recurrence, tag-carried h exchange.
// 64 blocks = (4 batch-groups x 16 k-groups); block owns 16 batches x 32 cols.
// h published as relaxed agent-scope u64 = (h1,h0)<<32 | step_tag -> no flags,
// no release drain, one L3 hop publish->detect. gx prefetched one step ahead.
// Hs LDS double-buffered -> single __syncthreads per step (stage->MFMA only).
// c state lives in registers (lane-private address).
// ---------------------------------------------------------------------------
__global__ void __launch_bounds__(256)
lstm_rec(const u16* __restrict__ gx, const u16* __restrict__ whp,
         u64* hbuf, float* __restrict__ out)
{
  __shared__ __align__(16) char lds[32768 + 8192];
  u16*  Hs  = (u16*)lds;                    // h tile, fragment order, 2 x 16KB
  float* scr = (float*)(lds + 32768);       // per-wave gate scratch, 4x2KB

  const int tid  = threadIdx.x;
  const int lane = tid & 63;
  const int w    = tid >> 6;
  const int bg   = blockIdx.x >> 4;         // 0..3  batch group (16 batches)
  const int kg   = blockIdx.x & 15;         // 0..15 k group (32 hidden cols)

  // preload this wave's 32 Wh B-fragments into registers
  bf16x8 wf0[16], wf1[16];
  {
    const int n0   = kg * 128 + (2 * w) * 16 + (lane & 15);
    const int koff = (lane >> 4) << 3;
#pragma unroll
    for (int kb = 0; kb < 16; ++kb) {
      wf0[kb] = *(const bf16x8*)(whp + (long)n0 * 512 + kb * 32 + koff);
      wf1[kb] = *(const bf16x8*)(whp + (long)(n0 + 16) * 512 + kb * 32 + koff);
    }
  }

  // ---- staging constants: thread stages row (tid>>4), kp = s*16 + (tid&15)
  const int srow = tid >> 4;
  const u64* hsrc = hbuf + (long)(bg * 16 + srow) * 256 + (tid & 15);
  const int sl = srow + (((tid & 15) >> 2) << 4);           // A-frag lane index
  u16* sdst = Hs + sl * 8 + 2 * (tid & 3);                  // + s*512 + par*8192

  // ---- cell-phase constants: lane owns cells (b16, klw) and (b16, klw+1)
  const int id    = lane * 2;
  const int b16   = id >> 3;
  const int klw   = id & 7;                 // even
  const int kl    = w * 8 + klw;            // 0..31 within block
  const int kgl   = kg * 32 + kl;           // 0..511 global hidden col
  const int bglob = bg * 16 + b16;

  const u16* gxp0 = gx + (long)bglob * G_ + (long)kgl * 4;
  uint4 gq = *(const uint4*)gxp0;           // prefetch gx for t=0

  u64* hdst = hbuf + (long)bglob * 256 + (kgl >> 1);
  float c0 = 0.f, c1 = 0.f;                 // cell state in registers

  for (int t = 0; t < T_; ++t) {
    const int par = t & 1;

    // ---- poll tagged h_t (my 16 words) until every tag == t ----
    const u64* hp_ = hsrc + (size_t)par * 16384;
    u64 v[16];
    for (;;) {
      bool ok = true;
#pragma unroll
      for (int s = 0; s < 16; ++s)
        v[s] = __hip_atomic_load(hp_ + s * 16, __ATOMIC_RELAXED, __HIP_MEMORY_SCOPE_AGENT);
#pragma unroll
      for (int s = 0; s < 16; ++s) ok &= ((u32)v[s] == (u32)t);
      if (ok) break;
      __builtin_amdgcn_s_sleep(1);
    }

    // ---- strip tags, stage into A-fragment-order LDS (buffer par) ----
    u16* sd = sdst + par * 8192;
#pragma unroll
    for (int s = 0; s < 16; ++s)
      *(u32*)(sd + s * 512) = (u32)(v[s] >> 32);
    __syncthreads();                        // the only barrier per step

    // ---- gates(block cols) = h_t @ Wh_chunk^T  (2x8-deep chains per acc) ----
    const u16* Hb = Hs + par * 8192;
    f32x4 acc0a = {0.f,0.f,0.f,0.f}, acc0b = {0.f,0.f,0.f,0.f};
    f32x4 acc1a = {0.f,0.f,0.f,0.f}, acc1b = {0.f,0.f,0.f,0.f};
#pragma unroll
    for (int kb = 0; kb < 16; kb += 2) {
      bf16x8 aA = *(const bf16x8*)(Hb + kb * 512 + lane * 8);
      bf16x8 aB = *(const bf16x8*)(Hb + (kb + 1) * 512 + lane * 8);
      acc0a = __builtin_amdgcn_mfma_f32_16x16x32_bf16(aA, wf0[kb],     acc0a, 0, 0, 0);
      acc1a = __builtin_amdgcn_mfma_f32_16x16x32_bf16(aA, wf1[kb],     acc1a, 0, 0, 0);
      acc0b = __builtin_amdgcn_mfma_f32_16x16x32_bf16(aB, wf0[kb + 1], acc0b, 0, 0, 0);
      acc1b = __builtin_amdgcn_mfma_f32_16x16x32_bf16(aB, wf1[kb + 1], acc1b, 0, 0, 0);
    }
    f32x4 acc0 = acc0a + acc0b;
    f32x4 acc1 = acc1a + acc1b;

    // ---- scatter C frags to per-wave scratch [b][klw][gate] (same-wave) ----
    float* sw = scr + w * 512;
    {
      const int colq = (lane & 15) >> 2;
      const int gidx = lane & 3;
      const int bq   = (lane >> 4) << 2;
#pragma unroll
      for (int r = 0; r < 4; ++r) {
        sw[((bq + r) * 8 + colq) * 4 + gidx]     = acc0[r];
        sw[((bq + r) * 8 + 4 + colq) * 4 + gidx] = acc1[r];
      }
    }

    // ---- cell update (gq was prefetched a full step ago) ----
    uint4 gqc = gq;
    if (t + 1 < T_) gq = *(const uint4*)(gxp0 + (long)(t + 1) * (B_ * G_));

    const u16* gu = (const u16*)&gqc;
    f32x4 ga = *(const f32x4*)(sw + (b16 * 8 + klw) * 4);
    f32x4 gb = *(const f32x4*)(sw + (b16 * 8 + klw + 1) * 4);

    float i0 = sigmoidf_(ga[0] + bf2f(gu[0]));
    float f0 = sigmoidf_(ga[1] + bf2f(gu[1]));
    float g0 = tanhf_   (ga[2] + bf2f(gu[2]));
    float o0 = sigmoidf_(ga[3] + bf2f(gu[3]));
    float i1 = sigmoidf_(gb[0] + bf2f(gu[4]));
    float f1 = sigmoidf_(gb[1] + bf2f(gu[5]));
    float g1 = tanhf_   (gb[2] + bf2f(gu[6]));
    float o1 = sigmoidf_(gb[3] + bf2f(gu[7]));
    float cn0 = f0 * c0 + i0 * g0;
    float cn1 = f1 * c1 + i1 * g1;
    float h0 = o0 * tanhf_(cn0);
    float h1 = o1 * tanhf_(cn1);
    c0 = cn0;
    c1 = cn1;

    // ---- publish h_{t+1} FIRST: tag travels atomically with the data ----
    u32 hp = ((u32)f2bf(h1) << 16) | (u32)f2bf(h0);
    u64 tv = ((u64)hp << 32) | (u32)(t + 1);
    __hip_atomic_store(hdst + (size_t)((t + 1) & 1) * 16384, tv,
                       __ATOMIC_RELAXED, __HIP_MEMORY_SCOPE_AGENT);

    float2 hv; hv.x = h0; hv.y = h1;
    *(float2*)(out + ((long)bglob * T_ + t) * H_ + kgl) = hv;   // output[b][t][k]

    if (t == T_ - 1) {
      float2 cv; cv.x = cn0; cv.y = cn1;
      *(float2*)(out + (size_t)B_ * T_ * H_ + (long)bglob * H_ + kgl) = hv;            // h_n
      *(float2*)(out + (size_t)B_ * T_ * H_ + B_ * H_ + (long)bglob * H_ + kgl) = cv;  // c_n
    }
    // no end-of-step barrier: Hs is double-buffered; the tag protocol proves
    // no producer can overwrite a buffer a sibling wave still reads.
  }
}

extern "C" void kernel_launch(void* const* d_in, const int* in_sizes, int n_in,
                              void* d_out, int out_size, void* d_ws, size_t ws_size,
                              hipStream_t stream)
{
  (void)in_sizes; (void)n_in; (void)out_size;
  if (ws_size < WS_NEEDED) return;   // need ~645 MB scratch

  const float* x  = (const float*)d_in[0];
  const float* Wx = (const float*)d_in[1];
  const float* bx = (const float*)d_in[2];
  const float* Wh = (const float*)d_in[3];
  const float* bh = (const float*)d_in[4];
  float* out = (float*)d_out;
  char* ws = (char*)d_ws;
  u16* xb     = (u16*)(ws + OFF_XB);
  u16* gx     = (u16*)(ws + OFF_GX);
  u16* wxp    = (u16*)(ws + OFF_WXP);
  u16* whp    = (u16*)(ws + OFF_WHP);
  float* bias = (float*)(ws + OFF_BIAS);
  u64* hbuf   = (u64*)(ws + OFF_HBUF);

  prep_misc<<<4096, 256, 0, stream>>>(Wx, bx, Wh, bh, wxp, whp, bias, (u32*)hbuf);
  conv_x<<<65536, 256, 0, stream>>>(x, xb);
  gemm_gates<<<dim3(16, 1024), 256, 0, stream>>>(xb, wxp, bias, gx);
  lstm_rec<<<64, 256, 0, stream>>>(gx, whp, hbuf, out);
}